// Round 1
// baseline (846.301 us; speedup 1.0000x reference)
//
#include <hip/hip_runtime.h>

#define THREADS 512

// ---- LDS layout (float offsets; every matrix 16B-aligned) ----
// Per team block:
//   W1  [50][52]   (51 in-dims padded to 52, row-major, out x in)
//   W2T [50][28]   (transposed: [in=50][out=25 padded to 28])
//   W3T [25][12]   (transposed: [in=25][out=10 padded to 12])
//   b1  [52], b2 [28], b3 [12]
#define OFF_W1   0
#define OFF_W2T  2600
#define OFF_W3T  4000
#define OFF_B1   4300
#define OFF_B2   4352
#define OFF_B3   4380
#define TEAM_SZ  4392
#define OFF_WF   (2 * TEAM_SZ)        // [2][100]
#define OFF_BF   (OFF_WF + 200)       // [4]
#define LDS_FLOATS (OFF_BF + 4)       // 8988 floats = 35952 B

__device__ __forceinline__ void stage_pad(float* dst, const float* __restrict__ src,
                                          int rows, int cols, int pcols, int tid) {
    for (int i = tid; i < rows * pcols; i += THREADS) {
        int r = i / pcols, c = i - r * pcols;
        dst[i] = (c < cols) ? src[r * cols + c] : 0.0f;
    }
}
// dst[r*pcols+c] = src[c*rows+r]  (transpose-stage; src is [cols][rows] row-major)
__device__ __forceinline__ void stage_padT(float* dst, const float* __restrict__ src,
                                           int rows, int cols, int pcols, int tid) {
    for (int i = tid; i < rows * pcols; i += THREADS) {
        int r = i / pcols, c = i - r * pcols;
        dst[i] = (c < cols) ? src[c * rows + r] : 0.0f;
    }
}

__global__ __launch_bounds__(THREADS, 4)   // 4 waves/SIMD -> VGPR cap 128, 2 blocks/CU
void match_predict(const float* __restrict__ feat, const float* __restrict__ emb,
                   const float* __restrict__ W1a, const float* __restrict__ b1a,
                   const float* __restrict__ W2a, const float* __restrict__ b2a,
                   const float* __restrict__ W3a, const float* __restrict__ b3a,
                   const float* __restrict__ W1b, const float* __restrict__ b1b,
                   const float* __restrict__ W2b, const float* __restrict__ b2b,
                   const float* __restrict__ W3b, const float* __restrict__ b3b,
                   const float* __restrict__ Wf, const float* __restrict__ bf,
                   float* __restrict__ out, int nB)
{
    __shared__ __align__(16) float lds[LDS_FLOATS];
    const int tid = threadIdx.x;

    stage_pad (lds + OFF_W1,            W1a, 50, 51, 52, tid);
    stage_padT(lds + OFF_W2T,           W2a, 50, 25, 28, tid);
    stage_padT(lds + OFF_W3T,           W3a, 25, 10, 12, tid);
    stage_pad (lds + OFF_B1,            b1a,  1, 50, 52, tid);
    stage_pad (lds + OFF_B2,            b2a,  1, 25, 28, tid);
    stage_pad (lds + OFF_B3,            b3a,  1, 10, 12, tid);
    stage_pad (lds + TEAM_SZ + OFF_W1,  W1b, 50, 51, 52, tid);
    stage_padT(lds + TEAM_SZ + OFF_W2T, W2b, 50, 25, 28, tid);
    stage_padT(lds + TEAM_SZ + OFF_W3T, W3b, 25, 10, 12, tid);
    stage_pad (lds + TEAM_SZ + OFF_B1,  b1b,  1, 50, 52, tid);
    stage_pad (lds + TEAM_SZ + OFF_B2,  b2b,  1, 25, 28, tid);
    stage_pad (lds + TEAM_SZ + OFF_B3,  b3b,  1, 10, 12, tid);
    stage_pad (lds + OFF_WF,            Wf,   2, 100, 100, tid);
    stage_pad (lds + OFF_BF,            bf,   1, 2, 4, tid);
    __syncthreads();

    const int g = blockIdx.x * THREADS + tid;
    if (g >= nB) return;

    const float* f = feat + (size_t)g * 12;
    const float g1 = f[0];
    const float g2 = f[1];

    float out0 = lds[OFF_BF + 0];
    float out1 = lds[OFF_BF + 1];

    #pragma clang loop unroll(disable)
    for (int team = 0; team < 2; ++team) {
        const float* Wb = lds + team * TEAM_SZ;
        const float gl = team ? g2 : g1;

        #pragma clang loop unroll(disable)
        for (int c = 0; c < 5; ++c) {
            const int ci = (int)f[2 + team * 5 + c];
            const float* e = emb + (size_t)ci * 50;

            // x = [emb_row(50), glicko, 0-pad]
            float x[52];
            #pragma unroll
            for (int k = 0; k < 25; ++k) {
                float2 v = *reinterpret_cast<const float2*>(e + 2 * k);
                x[2 * k]     = v.x;
                x[2 * k + 1] = v.y;
            }
            x[50] = gl;
            x[51] = 0.0f;

            float h2acc[25];
            #pragma unroll
            for (int m = 0; m < 25; ++m) h2acc[m] = 0.0f;

            // Layer 1 (51->50) cascaded with layer-2 accumulation (50->25):
            // per j: h1_j = relu(W1[j,:].x + b1[j]); h2acc[:] += W2T[j,:] * h1_j
            for (int j = 0; j < 50; ++j) {
                const float4* w1row = reinterpret_cast<const float4*>(Wb + OFF_W1 + j * 52);
                float a0 = 0.f, a1 = 0.f, a2 = 0.f, a3 = 0.f;
                #pragma unroll
                for (int q = 0; q < 13; ++q) {
                    float4 w = w1row[q];
                    a0 = fmaf(w.x, x[4 * q + 0], a0);
                    a1 = fmaf(w.y, x[4 * q + 1], a1);
                    a2 = fmaf(w.z, x[4 * q + 2], a2);
                    a3 = fmaf(w.w, x[4 * q + 3], a3);
                }
                float h1 = (a0 + a1) + (a2 + a3) + Wb[OFF_B1 + j];
                h1 = fmaxf(h1, 0.0f);

                const float4* w2row = reinterpret_cast<const float4*>(Wb + OFF_W2T + j * 28);
                #pragma unroll
                for (int q = 0; q < 6; ++q) {
                    float4 w = w2row[q];
                    h2acc[4 * q + 0] = fmaf(w.x, h1, h2acc[4 * q + 0]);
                    h2acc[4 * q + 1] = fmaf(w.y, h1, h2acc[4 * q + 1]);
                    h2acc[4 * q + 2] = fmaf(w.z, h1, h2acc[4 * q + 2]);
                    h2acc[4 * q + 3] = fmaf(w.w, h1, h2acc[4 * q + 3]);
                }
                h2acc[24] = fmaf(Wb[OFF_W2T + j * 28 + 24], h1, h2acc[24]);
            }

            // Layer 3 (25->10), fully unrolled
            float h3acc[10];
            #pragma unroll
            for (int t = 0; t < 10; ++t) h3acc[t] = Wb[OFF_B3 + t];
            #pragma unroll
            for (int m = 0; m < 25; ++m) {
                float h2 = fmaxf(h2acc[m] + Wb[OFF_B2 + m], 0.0f);
                const float* w3row = Wb + OFF_W3T + m * 12;
                float4 wA = *reinterpret_cast<const float4*>(w3row + 0);
                float4 wB = *reinterpret_cast<const float4*>(w3row + 4);
                float2 wC = *reinterpret_cast<const float2*>(w3row + 8);
                h3acc[0] = fmaf(wA.x, h2, h3acc[0]);
                h3acc[1] = fmaf(wA.y, h2, h3acc[1]);
                h3acc[2] = fmaf(wA.z, h2, h3acc[2]);
                h3acc[3] = fmaf(wA.w, h2, h3acc[3]);
                h3acc[4] = fmaf(wB.x, h2, h3acc[4]);
                h3acc[5] = fmaf(wB.y, h2, h3acc[5]);
                h3acc[6] = fmaf(wB.z, h2, h3acc[6]);
                h3acc[7] = fmaf(wB.w, h2, h3acc[7]);
                h3acc[8] = fmaf(wC.x, h2, h3acc[8]);
                h3acc[9] = fmaf(wC.y, h2, h3acc[9]);
            }

            // Final layer contribution for this champion's 10 outputs
            const int i0 = team * 50 + c * 10;
            #pragma unroll
            for (int t = 0; t < 10; ++t) {
                float h3 = fmaxf(h3acc[t], 0.0f);
                out0 = fmaf(lds[OFF_WF + i0 + t],       h3, out0);
                out1 = fmaf(lds[OFF_WF + 100 + i0 + t], h3, out1);
            }
        }
    }

    reinterpret_cast<float2*>(out)[g] = make_float2(out0, out1);
}

extern "C" void kernel_launch(void* const* d_in, const int* in_sizes, int n_in,
                              void* d_out, int out_size, void* d_ws, size_t ws_size,
                              hipStream_t stream) {
    const float* feat = (const float*)d_in[0];
    const float* emb  = (const float*)d_in[1];
    const float* W1a  = (const float*)d_in[2];
    const float* b1a  = (const float*)d_in[3];
    const float* W2a  = (const float*)d_in[4];
    const float* b2a  = (const float*)d_in[5];
    const float* W3a  = (const float*)d_in[6];
    const float* b3a  = (const float*)d_in[7];
    const float* W1b  = (const float*)d_in[8];
    const float* b1b  = (const float*)d_in[9];
    const float* W2b  = (const float*)d_in[10];
    const float* b2b  = (const float*)d_in[11];
    const float* W3b  = (const float*)d_in[12];
    const float* b3b  = (const float*)d_in[13];
    const float* Wf   = (const float*)d_in[14];
    const float* bf   = (const float*)d_in[15];
    float* out = (float*)d_out;

    const int nB = in_sizes[0] / 12;
    const int blocks = (nB + THREADS - 1) / THREADS;
    match_predict<<<blocks, THREADS, 0, stream>>>(feat, emb,
        W1a, b1a, W2a, b2a, W3a, b3a,
        W1b, b1b, W2b, b2b, W3b, b3b,
        Wf, bf, out, nB);
}

// Round 2
// 358.279 us; speedup vs baseline: 2.3621x; 2.3621x over previous
//
#include <hip/hip_runtime.h>

#define THREADS 256

// All weights are read with wave-uniform addresses directly from global memory:
// the compiler scalarizes these to s_load -> SGPRs (scalar pipe + K$), and
// v_fma_f32 consumes 1 SGPR operand for free. No LDS, no staging barrier.
// amdgpu_waves_per_eu(3,4) pins the VGPR budget to ~170 so the x[52]/h2acc[25]
// working set stays in registers (round-1 failure: allocator chose 64 VGPRs and
// spilled 2.1 GB of scratch traffic).
__global__ __launch_bounds__(THREADS)
__attribute__((amdgpu_waves_per_eu(3, 4)))
void match_predict(const float* __restrict__ feat, const float* __restrict__ emb,
                   const float* __restrict__ W1a, const float* __restrict__ b1a,
                   const float* __restrict__ W2a, const float* __restrict__ b2a,
                   const float* __restrict__ W3a, const float* __restrict__ b3a,
                   const float* __restrict__ W1b, const float* __restrict__ b1b,
                   const float* __restrict__ W2b, const float* __restrict__ b2b,
                   const float* __restrict__ W3b, const float* __restrict__ b3b,
                   const float* __restrict__ Wf, const float* __restrict__ bf,
                   float* __restrict__ out, int nB)
{
    const int g = blockIdx.x * THREADS + threadIdx.x;
    if (g >= nB) return;
    const float* __restrict__ f = feat + (size_t)g * 12;

    float out0 = bf[0];
    float out1 = bf[1];

    #pragma clang loop unroll(disable)
    for (int team = 0; team < 2; ++team) {
        const float* __restrict__ W1 = team ? W1b : W1a;
        const float* __restrict__ B1 = team ? b1b : b1a;
        const float* __restrict__ W2 = team ? W2b : W2a;
        const float* __restrict__ B2 = team ? b2b : b2a;
        const float* __restrict__ W3 = team ? W3b : W3a;
        const float* __restrict__ B3 = team ? b3b : b3a;
        const float gl = f[team];           // per-lane load (f[0] / f[1])

        #pragma clang loop unroll(disable)
        for (int c = 0; c < 5; ++c) {
            const int ci = (int)f[2 + team * 5 + c];
            const float* __restrict__ e = emb + (size_t)ci * 50;

            // x = [emb_row(50), glicko, 0] -- all statically indexed (stays in VGPRs)
            float x[52];
            #pragma unroll
            for (int k = 0; k < 25; ++k) {
                float2 v = *reinterpret_cast<const float2*>(e + 2 * k);
                x[2 * k]     = v.x;
                x[2 * k + 1] = v.y;
            }
            x[50] = gl;
            x[51] = 0.0f;

            float h2acc[25];
            #pragma unroll
            for (int m = 0; m < 25; ++m) h2acc[m] = 0.0f;

            // Layer 1 (51->50) cascaded with layer 2 accumulation (50->25).
            // h1_j is a scalar; h2acc is statically indexed; weight addresses are
            // loop-uniform -> s_load. No dynamically-indexed register arrays.
            #pragma clang loop unroll_count(2)
            for (int j = 0; j < 50; ++j) {
                const float* __restrict__ w = W1 + j * 51;
                float a0 = B1[j], a1 = 0.f, a2 = 0.f, a3 = 0.f;
                #pragma unroll
                for (int q = 0; q < 12; ++q) {
                    a0 = fmaf(w[4 * q + 0], x[4 * q + 0], a0);
                    a1 = fmaf(w[4 * q + 1], x[4 * q + 1], a1);
                    a2 = fmaf(w[4 * q + 2], x[4 * q + 2], a2);
                    a3 = fmaf(w[4 * q + 3], x[4 * q + 3], a3);
                }
                a0 = fmaf(w[48], x[48], a0);
                a1 = fmaf(w[49], x[49], a1);
                a2 = fmaf(w[50], x[50], a2);
                const float h1 = fmaxf((a0 + a1) + (a2 + a3), 0.0f);

                // h2acc[m] += W2[m][j] * h1   (W2 column j: scattered s_load_dword)
                #pragma unroll
                for (int m = 0; m < 25; ++m)
                    h2acc[m] = fmaf(W2[m * 50 + j], h1, h2acc[m]);
            }

            // Layer 3 (25->10), cascaded: h3[t] += W3[t][m] * relu(h2_m + b2_m)
            float h3[10];
            #pragma unroll
            for (int t = 0; t < 10; ++t) h3[t] = B3[t];
            #pragma unroll
            for (int m = 0; m < 25; ++m) {
                const float h2 = fmaxf(h2acc[m] + B2[m], 0.0f);
                #pragma unroll
                for (int t = 0; t < 10; ++t)
                    h3[t] = fmaf(W3[t * 25 + m], h2, h3[t]);
            }

            // Final-layer contribution of this champion's 10 activations
            const int i0 = team * 50 + c * 10;
            #pragma unroll
            for (int t = 0; t < 10; ++t) {
                const float v = fmaxf(h3[t], 0.0f);
                out0 = fmaf(Wf[i0 + t],       v, out0);
                out1 = fmaf(Wf[100 + i0 + t], v, out1);
            }
        }
    }

    reinterpret_cast<float2*>(out)[g] = make_float2(out0, out1);
}

extern "C" void kernel_launch(void* const* d_in, const int* in_sizes, int n_in,
                              void* d_out, int out_size, void* d_ws, size_t ws_size,
                              hipStream_t stream) {
    const float* feat = (const float*)d_in[0];
    const float* emb  = (const float*)d_in[1];
    const float* W1a  = (const float*)d_in[2];
    const float* b1a  = (const float*)d_in[3];
    const float* W2a  = (const float*)d_in[4];
    const float* b2a  = (const float*)d_in[5];
    const float* W3a  = (const float*)d_in[6];
    const float* b3a  = (const float*)d_in[7];
    const float* W1b  = (const float*)d_in[8];
    const float* b1b  = (const float*)d_in[9];
    const float* W2b  = (const float*)d_in[10];
    const float* b2b  = (const float*)d_in[11];
    const float* W3b  = (const float*)d_in[12];
    const float* b3b  = (const float*)d_in[13];
    const float* Wf   = (const float*)d_in[14];
    const float* bf   = (const float*)d_in[15];
    float* out = (float*)d_out;

    const int nB = in_sizes[0] / 12;
    const int blocks = (nB + THREADS - 1) / THREADS;
    match_predict<<<blocks, THREADS, 0, stream>>>(feat, emb,
        W1a, b1a, W2a, b2a, W3a, b3a,
        W1b, b1b, W2b, b2b, W3b, b3b,
        Wf, bf, out, nB);
}

// Round 3
// 164.982 us; speedup vs baseline: 5.1297x; 2.1716x over previous
//
#include <hip/hip_runtime.h>

#define TPB 256

// ---- d_ws float layout (all offsets 16B-aligned) ----
// pre[2][170][52] : W1[:, :50] @ emb[c] + b1  (52-padded rows, pads = 0)
// w1g[2][56]      : W1[j][50] (glicko column), pads = 0
// w2t[2][50][28]  : W2 transposed ([j][m], m-padded to 28)
// w3t[2][25][12]  : W3 transposed ([m][t], t-padded to 12)
#define PRE_OFF   0
#define PRE_TEAM  (170 * 52)                  // 8840
#define W1G_OFF   (2 * PRE_TEAM)              // 17680
#define W2T_OFF   (W1G_OFF + 2 * 56)          // 17792
#define W2T_TEAM  (50 * 28)
#define W3T_OFF   (W2T_OFF + 2 * W2T_TEAM)    // 20592
#define W3T_TEAM  (25 * 12)
#define WS_FLOATS (W3T_OFF + 2 * W3T_TEAM)    // 21192 floats = 84768 B

__global__ void precompute(const float* __restrict__ emb,
                           const float* __restrict__ W1a, const float* __restrict__ b1a,
                           const float* __restrict__ W2a, const float* __restrict__ W3a,
                           const float* __restrict__ W1b, const float* __restrict__ b1b,
                           const float* __restrict__ W2b, const float* __restrict__ W3b,
                           float* __restrict__ ws)
{
    const int team = blockIdx.y;
    const float* __restrict__ W1 = team ? W1b : W1a;
    const float* __restrict__ B1 = team ? b1b : b1a;
    const float* __restrict__ W2 = team ? W2b : W2a;
    const float* __restrict__ W3 = team ? W3b : W3a;
    const int tid = threadIdx.x;

    if (blockIdx.x < 170) {
        const int c = blockIdx.x;
        float* prow = ws + PRE_OFF + team * PRE_TEAM + c * 52;
        if (tid < 52) {
            float acc = 0.0f;
            if (tid < 50) {
                acc = B1[tid];
                for (int k = 0; k < 50; ++k)
                    acc = fmaf(W1[tid * 51 + k], emb[c * 50 + k], acc);
            }
            prow[tid] = acc;
        }
    } else {
        float* w1g = ws + W1G_OFF + team * 56;
        for (int i = tid; i < 56; i += 64)
            w1g[i] = (i < 50) ? W1[i * 51 + 50] : 0.0f;
        float* w2t = ws + W2T_OFF + team * W2T_TEAM;
        for (int i = tid; i < 50 * 28; i += 64) {
            int j = i / 28, m = i - j * 28;
            w2t[i] = (m < 25) ? W2[m * 50 + j] : 0.0f;
        }
        float* w3t = ws + W3T_OFF + team * W3T_TEAM;
        for (int i = tid; i < 25 * 12; i += 64) {
            int mm = i / 12, t = i - mm * 12;
            w3t[i] = (t < 10) ? W3[t * 25 + mm] : 0.0f;
        }
    }
}

// Waves 0-1 of each block: team A for samples [base, base+128); waves 2-3: team B.
// team is wave-uniform -> all weight/table base addresses stay scalar (s_load).
// Partial (out0,out1) combined through LDS.
__global__ __launch_bounds__(TPB)
__attribute__((amdgpu_waves_per_eu(4, 8)))
void match_predict(const float* __restrict__ feat, const float* __restrict__ ws,
                   const float* __restrict__ b2a, const float* __restrict__ b3a,
                   const float* __restrict__ b2b, const float* __restrict__ b3b,
                   const float* __restrict__ Wf, const float* __restrict__ bf,
                   float* __restrict__ out, int nB)
{
    __shared__ float2 part[128];
    const int tid  = threadIdx.x;
    const int sidx = tid & 127;
    const int team = __builtin_amdgcn_readfirstlane(tid >> 7);  // wave-uniform

    const int s = blockIdx.x * 128 + sidx;
    const bool active = s < nB;

    float t0 = 0.0f, t1 = 0.0f;

    if (active) {
        const float4* f4 = reinterpret_cast<const float4*>(feat + (size_t)s * 12);
        const float4 v0 = f4[0], v1 = f4[1], v2 = f4[2];
        const float fr[12] = {v0.x, v0.y, v0.z, v0.w, v1.x, v1.y, v1.z, v1.w,
                              v2.x, v2.y, v2.z, v2.w};
        const float gl = team ? fr[1] : fr[0];
        int ci[5];
        #pragma unroll
        for (int c = 0; c < 5; ++c)
            ci[c] = (int)(team ? fr[7 + c] : fr[2 + c]);

        const float* __restrict__ pre = ws + PRE_OFF + team * PRE_TEAM;
        const float* __restrict__ w1g = ws + W1G_OFF + team * 56;
        const float* __restrict__ w2t = ws + W2T_OFF + team * W2T_TEAM;
        const float* __restrict__ w3t = ws + W3T_OFF + team * W3T_TEAM;
        const float* __restrict__ B2  = team ? b2b : b2a;
        const float* __restrict__ B3  = team ? b3b : b3a;
        const float* __restrict__ wf0 = Wf + team * 50;
        const float* __restrict__ wf1 = Wf + 100 + team * 50;

        #pragma clang loop unroll(disable)
        for (int c = 0; c < 5; ++c) {
            const float* prowf = pre + ci[c] * 52;
            const float4* prow = reinterpret_cast<const float4*>(prowf);

            float h2acc[25];
            #pragma unroll
            for (int m = 0; m < 25; ++m) h2acc[m] = 0.0f;

            // Layer 1 residual (glicko term) cascaded with layer 2.
            #pragma clang loop unroll_count(2)
            for (int jq = 0; jq < 12; ++jq) {
                const float4 p = prow[jq];
                const float pc[4] = {p.x, p.y, p.z, p.w};
                #pragma unroll
                for (int u = 0; u < 4; ++u) {
                    const int j = 4 * jq + u;
                    const float h1 = fmaxf(fmaf(w1g[j], gl, pc[u]), 0.0f);
                    const float* __restrict__ w2r = w2t + j * 28;
                    #pragma unroll
                    for (int m = 0; m < 25; ++m)
                        h2acc[m] = fmaf(w2r[m], h1, h2acc[m]);
                }
            }
            {   // j = 48, 49 tail
                const float2 pt = *reinterpret_cast<const float2*>(prowf + 48);
                const float pc[2] = {pt.x, pt.y};
                #pragma unroll
                for (int u = 0; u < 2; ++u) {
                    const int j = 48 + u;
                    const float h1 = fmaxf(fmaf(w1g[j], gl, pc[u]), 0.0f);
                    const float* __restrict__ w2r = w2t + j * 28;
                    #pragma unroll
                    for (int m = 0; m < 25; ++m)
                        h2acc[m] = fmaf(w2r[m], h1, h2acc[m]);
                }
            }

            // Layer 3 (25 -> 10), cascaded
            float h3[10];
            #pragma unroll
            for (int t = 0; t < 10; ++t) h3[t] = B3[t];
            #pragma unroll
            for (int m = 0; m < 25; ++m) {
                const float h2 = fmaxf(h2acc[m] + B2[m], 0.0f);
                const float* __restrict__ w3r = w3t + m * 12;
                #pragma unroll
                for (int t = 0; t < 10; ++t)
                    h3[t] = fmaf(w3r[t], h2, h3[t]);
            }

            // Final-layer partial for this champion's 10 activations
            const int i0 = c * 10;
            #pragma unroll
            for (int t = 0; t < 10; ++t) {
                const float v = fmaxf(h3[t], 0.0f);
                t0 = fmaf(wf0[i0 + t], v, t0);
                t1 = fmaf(wf1[i0 + t], v, t1);
            }
        }
    }

    if (team == 0 && active) part[sidx] = make_float2(t0, t1);
    __syncthreads();
    if (team == 1 && active) {
        const float2 p = part[sidx];
        reinterpret_cast<float2*>(out)[s] =
            make_float2(p.x + t0 + bf[0], p.y + t1 + bf[1]);
    }
}

extern "C" void kernel_launch(void* const* d_in, const int* in_sizes, int n_in,
                              void* d_out, int out_size, void* d_ws, size_t ws_size,
                              hipStream_t stream) {
    const float* feat = (const float*)d_in[0];
    const float* emb  = (const float*)d_in[1];
    const float* W1a  = (const float*)d_in[2];
    const float* b1a  = (const float*)d_in[3];
    const float* W2a  = (const float*)d_in[4];
    const float* b2a  = (const float*)d_in[5];
    const float* W3a  = (const float*)d_in[6];
    const float* b3a  = (const float*)d_in[7];
    const float* W1b  = (const float*)d_in[8];
    const float* b1b  = (const float*)d_in[9];
    const float* W2b  = (const float*)d_in[10];
    const float* b2b  = (const float*)d_in[11];
    const float* W3b  = (const float*)d_in[12];
    const float* b3b  = (const float*)d_in[13];
    const float* Wf   = (const float*)d_in[14];
    const float* bf   = (const float*)d_in[15];
    float* out = (float*)d_out;
    float* ws  = (float*)d_ws;

    const int nB = in_sizes[0] / 12;

    precompute<<<dim3(171, 2), 64, 0, stream>>>(emb, W1a, b1a, W2a, W3a,
                                                W1b, b1b, W2b, W3b, ws);

    const int blocks = (nB + 127) / 128;
    match_predict<<<blocks, TPB, 0, stream>>>(feat, ws, b2a, b3a, b2b, b3b,
                                              Wf, bf, out, nB);
}